// Round 10
// baseline (486.489 us; speedup 1.0000x reference)
//
#include <hip/hip_runtime.h>
#include <math.h>

// RealNVP, 8 layers, B=262144, H=128. Multi-kernel, 2 kernels/layer.
// k_bin: BN1 fold + rank + binning + hist + BN2 moment fold + BIN-SORTED
//        scatter (idx, per-(bin,block) chunk descriptors, global bin counts).
// k_step: rank-parallel (1 sample/thread); per touched bin: stage chunk
//        descriptors + dense BN2-folded (A,B,wf0,wf1) row in LDS; evaluate
//        st = sum wf*relu(Ax+B) directly. No segment tables, no prep2 kernel.

#define BN_ 262144
#define H_ 128
#define NBINS 129

// ws element offsets (4B units; int and float regions share the arena)
#define OFF_STAT 0                      // [l][16 slots][2] = 256
#define OFF_PM   256                    // [l][8 slots][256] = 16384 -> 16640
#define OFF_GBC  16640                  // int [l][132] = 1056 -> 17696
#define OFF_CNT  17696                  // int [132][256] = 33792 -> 51488
#define OFF_OFS  51488                  // int [132][256] = 33792 -> 85280
#define OFF_IDX  85280                  // int [BN] -> 347424
#define OFF_XP   347424                 // float2 xp[BN] -> 871712
#define OFF_SL   871712                 // float sldj[BN] -> 1133856
#define OFF_V2T  1133856                // float v2T[8][128][128] -> 1264928
#define OFF_WSC  1264928                // float [8][128] -> 1265952
#define OFF_S    1265952                // float2 ST[129][128] -> 1298976

// 256x1024: stats of x1 (layer-0 xin, 16 slots) + v2 transpose + wsc.
__global__ __launch_bounds__(1024) void k_init(const float* __restrict__ x,
    const float* __restrict__ v2, const float* __restrict__ g2,
    float* __restrict__ ws) {
    const int tid = threadIdx.x;
    __shared__ float rs[16], rss[16], w2[16];
    int b = blockIdx.x * 1024 + tid;
    float2 xv = ((const float2*)x)[b];
    float s1 = xv.y, s2 = xv.y * xv.y;
    for (int off = 32; off; off >>= 1) {
        s1 += __shfl_down(s1, off); s2 += __shfl_down(s2, off);
    }
    if ((tid & 63) == 0) { rs[tid>>6] = s1; rss[tid>>6] = s2; }
    __syncthreads();
    if (tid == 0) {
        float a = 0.f, c = 0.f;
        for (int w = 0; w < 16; w++) { a += rs[w]; c += rss[w]; }
        atomicAdd(&ws[OFF_STAT + (blockIdx.x & 15)*2], a);
        atomicAdd(&ws[OFF_STAT + (blockIdx.x & 15)*2 + 1], c);
    }
    if (blockIdx.x < 128) {
        const int l = blockIdx.x >> 4, i0 = (blockIdx.x & 15) * 8;
        const int iloc = tid >> 7, j = tid & 127;
        float val = v2[(l*H_ + i0 + iloc)*H_ + j];
        ws[OFF_V2T + (l*H_ + j)*H_ + i0 + iloc] = val;
        float s = val * val;
        for (int off = 32; off; off >>= 1) s += __shfl_down(s, off);
        if ((tid & 63) == 0) w2[tid >> 6] = s;
        __syncthreads();
        if (tid < 8)
            ws[OFF_WSC + l*H_ + i0 + tid] =
                g2[l*H_ + i0 + tid] / sqrtf(w2[2*tid] + w2[2*tid+1]);
    }
}

// 256x1024: BN1 fold + rank + binning + hist + BN2 moment fold + scatter.
__global__ __launch_bounds__(1024, 4) void k_bin(
    const float* __restrict__ x,
    const float* __restrict__ v1, const float* __restrict__ g1,
    const float* __restrict__ bn1g, const float* __restrict__ bn1b,
    const float* __restrict__ b2,
    float* __restrict__ ws, int l, int rev) {
    __shared__ float sA[H_], sC[H_], sTun[H_], sTs[H_], wscs[H_], b2s[H_];
    __shared__ int ordr[H_];
    __shared__ float pT1[8][H_], pT0[8][H_], pB1[8][H_], pB0[8][H_];
    __shared__ float scratch[5216];  // [0,2048) prank/red | [2048,5216) lb (8x396)
    __shared__ int binTotI[132], sBase[132];
    float* lb = scratch + 2048;
    const int tid = threadIdx.x;
    const int i = tid & 127, cc = tid >> 7;
    const float* v2T = ws + OFF_V2T + l*H_*H_;
    const int b = blockIdx.x * 1024 + tid;

    float xin;                        // early issue: hides HBM latency
    if (l == 0) xin = ((const float2*)x)[b].y;
    else {
        float2 xp = ((const float2*)(ws + OFF_XP))[b];
        xin = rev ? xp.y : xp.x;
    }

    if (tid < H_) {                   // phase 0: BN1 fold (block-redundant)
        float Ssum = 0.f, SSq = 0.f;
        #pragma unroll
        for (int s = 0; s < 16; ++s) {
            Ssum += ws[OFF_STAT + l*32 + 2*s];
            SSq  += ws[OFF_STAT + l*32 + 2*s + 1];
        }
        float mx = Ssum * (1.f / BN_);
        float vx = fmaxf(SSq * (1.f / BN_) - mx * mx, 0.f);
        float g1v = g1[l*H_ + tid];
        float w1 = (v1[l*H_ + tid] >= 0.f) ? g1v : -g1v;
        float r = rsqrtf(vx * g1v * g1v + 1e-5f);
        float a = w1 * r * bn1g[l*H_ + tid];
        float c = bn1b[l*H_ + tid] - mx * a;
        sA[tid] = a; sC[tid] = c;
        sTun[tid] = (a != 0.f) ? (-c / a) : 3.0e38f;
        wscs[tid] = ws[OFF_WSC + l*H_ + tid];
        b2s[tid] = b2[l*H_ + tid];
    }
    for (int e = tid; e < 3168; e += 1024) lb[e] = 0.f;
    __syncthreads();
    {                                 // phase 1: rank (8 partial segments)
        int* prank = (int*)scratch;
        float tj = sTun[i];
        int pr = 0;
        #pragma unroll
        for (int m = 0; m < 16; ++m) {
            int q = cc*16 + m;
            float tq = sTun[q];
            pr += (tq < tj || (tq == tj && q < i)) ? 1 : 0;
        }
        prank[cc*128 + i] = pr;
        __syncthreads();
        if (tid < H_) {
            int rk = 0;
            #pragma unroll
            for (int s = 0; s < 8; ++s) rk += prank[s*128 + tid];
            ordr[rk] = tid;
            sTs[rk] = sTun[tid];
        }
    }
    __syncthreads();
    float rT1_[16];
    int pos, rnk;
    {                                 // phase 2+3: bin/hist(+rank) + toggles
        int p = 0;
        #pragma unroll
        for (int s = 64; s; s >>= 1) p += (sTs[p + s - 1] < xin) ? s : 0;
        p += (sTs[p] < xin) ? 1 : 0;
        pos = p;
        float* lbr = lb + (tid & 7) * 396;
        rnk = (int)atomicAdd(&lbr[pos], 1.f);
        atomicAdd(&lbr[132 + pos], xin);
        atomicAdd(&lbr[264 + pos], xin * xin);

        float b1 = 0.f, b0 = 0.f, t1 = 0.f, t0 = 0.f;
        #pragma unroll
        for (int m = 0; m < 16; ++m) {
            int jm = ordr[cc*16 + m];
            float am = sA[jm], cm = sC[jm];
            float vm = v2T[jm*H_ + i];
            if ((am < 0.f) || (am == 0.f && cm > 0.f)) { b1 += vm*am; b0 += vm*cm; }
            float d1 = 0.f;
            if (am != 0.f) {
                float sg = (am > 0.f) ? 1.f : -1.f;
                d1 = sg*vm*am; t0 += sg*vm*cm;
            }
            rT1_[m] = d1; t1 += d1;
        }
        pT1[cc][i] = t1; pT0[cc][i] = t0; pB1[cc][i] = b1; pB0[cc][i] = b0;
    }
    __syncthreads();
    // phase 3.5: per-bin slot prefixes (cnt section) + merge sx/sxx to slot 0
    if (tid < NBINS) {
        int p = 0;
        #pragma unroll
        for (int c = 0; c < 8; ++c) {
            int cv = (int)lb[c*396 + tid];
            lb[c*396 + tid] = (float)p;       // prefix of slots < c
            p += cv;
        }
        binTotI[tid] = p;
    } else if (tid >= 132 && tid < 396) {
        float v = lb[tid];
        #pragma unroll
        for (int c = 1; c < 8; ++c) v += lb[c*396 + tid];
        lb[tid] = v;
    }
    __syncthreads();
    if (tid < 64) {                   // wave-0 exclusive scan of binTotI[0..128]
        int v0 = binTotI[tid], v1 = binTotI[64 + tid];
        int s0 = v0;
        #pragma unroll
        for (int off = 1; off < 64; off <<= 1) {
            int u = __shfl_up(s0, off); if (tid >= off) s0 += u;
        }
        int t0 = __shfl(s0, 63);
        int s1v = v1;
        #pragma unroll
        for (int off = 1; off < 64; off <<= 1) {
            int u = __shfl_up(s1v, off); if (tid >= off) s1v += u;
        }
        s1v += t0;
        int t1 = __shfl(s1v, 63);
        sBase[tid] = s0 - v0;
        sBase[64 + tid] = s1v - v1;
        if (tid == 0) sBase[128] = t1;
    }
    __syncthreads();
    {                                 // scatter + descriptors + global counts
        int slotPref = (int)lb[(tid & 7)*396 + pos];
        int myOfs = sBase[pos] + slotPref + rnk;
        ((int*)ws)[OFF_IDX + blockIdx.x*1024 + myOfs] = b;
        if (tid < NBINS) {
            ((int*)ws)[OFF_CNT + tid*256 + blockIdx.x] = binTotI[tid];
            ((int*)ws)[OFF_OFS + tid*256 + blockIdx.x] = sBase[tid];
            atomicAdd(((int*)ws) + OFF_GBC + l*132 + tid, binTotI[tid]);
        }
    }
    {                                 // phase 4: prefix walk (registers) + fold
        float S1 = 0.f, S0 = 0.f;
        #pragma unroll
        for (int c2 = 0; c2 < 8; ++c2) {
            S1 += pB1[c2][i]; S0 += pB0[c2][i];
            if (c2 < cc) { S1 += pT1[c2][i]; S0 += pT0[c2][i]; }
        }
        float wsci = wscs[i], b2i = b2s[i];
        float pm = 0.f, pe = 0.f;
        float2* STg = (float2*)(ws + OFF_S);
        #pragma unroll
        for (int r = 0; r < 16; ++r) {
            int k = 16*cc + r;
            float cn = (float)binTotI[k], sx = lb[132 + k], sxx = lb[264 + k];
            float A = wsci * S1;
            float B = fmaf(wsci, S0, b2i);
            if (blockIdx.x == 0) STg[k*H_ + i] = make_float2(A, B);
            pm += A*sx + B*cn;
            pe += A*A*sxx + 2.f*A*B*sx + B*B*cn;
            float d1 = rT1_[r];
            S1 += d1;
            S0 = fmaf(-d1, sTs[16*cc + r], S0);   // d0 = -d1*ts (exact algebra)
        }
        if (cc == 7) {                // bin 128 (no toggle after)
            float cn = (float)binTotI[128], sx = lb[260], sxx = lb[392];
            float A = wsci * S1;
            float B = fmaf(wsci, S0, b2i);
            if (blockIdx.x == 0) STg[128*H_ + i] = make_float2(A, B);
            pm += A*sx + B*cn;
            pe += A*A*sxx + 2.f*A*B*sx + B*B*cn;
        }
        float* red1 = scratch;        // reuse prank region (time-disjoint)
        float* red2 = scratch + 1024;
        red1[tid] = pm; red2[tid] = pe;
        __syncthreads();
        if (tid < H_) {
            float m = 0.f, e2 = 0.f;
            #pragma unroll
            for (int c2 = 0; c2 < 8; ++c2) {
                m += red1[c2*128 + tid]; e2 += red2[c2*128 + tid];
            }
            int slot = blockIdx.x & 7;
            atomicAdd(&ws[OFF_PM + l*2048 + slot*256 + tid], m);
            atomicAdd(&ws[OFF_PM + l*2048 + slot*256 + 128 + tid], e2);
        }
    }
}

// 1024x256: rank-parallel. Thread handles global bin-sorted rank r.
// Per touched bin: stage chunk descriptors + dense folded row; evaluate.
__global__ __launch_bounds__(256) void k_step(
    const float* __restrict__ x,
    const float* __restrict__ bn2g, const float* __restrict__ bn2b,
    const float* __restrict__ wf, const float* __restrict__ bf,
    float* __restrict__ ws, float* __restrict__ out,
    int l, int rev, int last) {
    __shared__ int sG[256];
    __shared__ int sCp[256];
    __shared__ int sOfs[256];
    __shared__ int wtot[4];
    __shared__ float4 af4[H_];
    __shared__ float2 rmb[H_];
    __shared__ int kk[2];
    __shared__ float rsc[8];
    const int tid = threadIdx.x, lane = tid & 63, wid = tid >> 6;

    // inclusive scan of global bin counts
    int g = (tid < NBINS) ? ((const int*)ws)[OFF_GBC + l*132 + tid] : 0;
    int sg = g;
    #pragma unroll
    for (int off = 1; off < 64; off <<= 1) {
        int u = __shfl_up(sg, off); if (lane >= off) sg += u;
    }
    if (lane == 63) wtot[wid] = sg;
    __syncthreads();
    int carry = 0;
    for (int w = 0; w < wid; ++w) carry += wtot[w];
    sg += carry;
    sG[tid] = sg;
    __syncthreads();
    const int r = blockIdx.x * 256 + tid;
    int myk = 0;
    #pragma unroll
    for (int st = 128; st; st >>= 1)
        if (myk + st <= NBINS && sG[myk + st - 1] <= r) myk += st;
    if (tid == 0) kk[0] = myk;
    if (tid == 255) kk[1] = myk;
    float wf0 = 0.f, wf1 = 0.f;
    if (tid < H_) {                   // layer-wide BN2 fold constants
        float pmv = 0.f, pev = 0.f;
        #pragma unroll
        for (int s = 0; s < 8; ++s) {
            pmv += ws[OFF_PM + l*2048 + s*256 + tid];
            pev += ws[OFF_PM + l*2048 + s*256 + 128 + tid];
        }
        float mean = pmv * (1.f / BN_);
        float var = fmaxf(pev * (1.f / BN_) - mean * mean, 0.f);
        float R = bn2g[l*H_ + tid] * rsqrtf(var + 1e-5f);
        rmb[tid] = make_float2(R, fmaf(-mean, R, bn2b[l*H_ + tid]));
        wf0 = wf[l*2*H_ + tid]; wf1 = wf[l*2*H_ + H_ + tid];
    }
    __syncthreads();
    const int k0 = kk[0], k1 = kk[1];
    const float2* STg = (const float2*)(ws + OFF_S);
    float bfx = bf[2*l], bfy = bf[2*l + 1];
    float y = 0.f;
    for (int k = k0; k <= k1; ++k) {
        int gk = sG[k] - (k ? sG[k-1] : 0);
        if (gk == 0) continue;
        __syncthreads();              // WAR: previous iter's LDS reads done
        int cv = ((const int*)ws)[OFF_CNT + k*256 + tid];
        int ov = ((const int*)ws)[OFF_OFS + k*256 + tid];
        int sc = cv;
        #pragma unroll
        for (int off = 1; off < 64; off <<= 1) {
            int u = __shfl_up(sc, off); if (lane >= off) sc += u;
        }
        if (lane == 63) wtot[wid] = sc;
        __syncthreads();
        int cr = 0;
        for (int w = 0; w < wid; ++w) cr += wtot[w];
        sc += cr;
        sCp[tid] = sc; sOfs[tid] = ov;
        if (tid < H_) {
            float2 st2 = STg[k*H_ + tid];
            float2 rb = rmb[tid];
            af4[tid] = make_float4(st2.x * rb.x, fmaf(st2.y, rb.x, rb.y), wf0, wf1);
        }
        __syncthreads();
        if (myk == k) {
            int rr = r - (k ? sG[k-1] : 0);
            int bl = 0;
            #pragma unroll
            for (int st = 128; st; st >>= 1)
                if (bl + st <= 256 && sCp[bl + st - 1] <= rr) bl += st;
            int within = rr - (bl ? sCp[bl-1] : 0);
            int smp = ((const int*)ws)[OFF_IDX + (bl << 10) + sOfs[bl] + within];
            float x0v, x1v, sl;
            if (l == 0) {
                float2 xv = ((const float2*)x)[smp];
                x0v = xv.x; x1v = xv.y; sl = 0.f;
            } else {
                float2 xp = ((const float2*)(ws + OFF_XP))[smp];
                x0v = xp.x; x1v = xp.y; sl = ws[OFF_SL + smp];
            }
            float xin = rev ? x1v : x0v;
            float xo  = rev ? x0v : x1v;
            float stx = bfx, sty = bfy;
            #pragma unroll 8
            for (int i2 = 0; i2 < H_; ++i2) {
                float4 q = af4[i2];
                float h = fmaxf(fmaf(xin, q.x, q.y), 0.f);
                stx = fmaf(q.z, h, stx);
                sty = fmaf(q.w, h, sty);
            }
            float sv = tanhf(stx);
            y = expf(sv) * xo + sty;
            sl += sv;
            if (!last) {
                float nx0 = rev ? y : x0v;
                float nx1 = rev ? x1v : y;
                ((float2*)(ws + OFF_XP))[smp] = make_float2(nx0, nx1);
                ws[OFF_SL + smp] = sl;
            } else {
                float z0 = 1.f / (1.f + expf(-x0v));
                float z1 = 1.f / (1.f + expf(-y));
                ((float2*)out)[smp] = make_float2(z0, z1);
                out[2*BN_ + smp] = sl + logf(z0 * (1.f - z0) + 1e-4f)
                                      + logf(z1 * (1.f - z1) + 1e-4f);
            }
        }
    }
    if (!last) {                      // fused next-layer xin stats
        float s1 = y, s2 = y * y;
        for (int off = 32; off; off >>= 1) {
            s1 += __shfl_down(s1, off); s2 += __shfl_down(s2, off);
        }
        if (lane == 0) { rsc[wid] = s1; rsc[4 + wid] = s2; }
        __syncthreads();
        if (tid == 0) {
            float aa = 0.f, cc2 = 0.f;
            for (int w = 0; w < 4; ++w) { aa += rsc[w]; cc2 += rsc[4 + w]; }
            int slot = blockIdx.x & 15;
            atomicAdd(&ws[OFF_STAT + (l+1)*32 + slot*2], aa);
            atomicAdd(&ws[OFF_STAT + (l+1)*32 + slot*2 + 1], cc2);
        }
    }
}

extern "C" void kernel_launch(void* const* d_in, const int* in_sizes, int n_in,
                              void* d_out, int out_size, void* d_ws, size_t ws_size,
                              hipStream_t stream) {
    const float* x    = (const float*)d_in[0];
    const float* v1   = (const float*)d_in[1];
    const float* g1   = (const float*)d_in[2];
    // d_in[3] = b1: cancels exactly inside BN1 (affine input), unused.
    const float* bn1g = (const float*)d_in[4];
    const float* bn1b = (const float*)d_in[5];
    const float* v2   = (const float*)d_in[6];
    const float* g2   = (const float*)d_in[7];
    const float* b2   = (const float*)d_in[8];
    const float* bn2g = (const float*)d_in[9];
    const float* bn2b = (const float*)d_in[10];
    const float* wf   = (const float*)d_in[11];
    const float* bf   = (const float*)d_in[12];
    float* ws  = (float*)d_ws;
    float* out = (float*)d_out;

    hipMemsetAsync(ws, 0, 17696 * sizeof(float), stream);  // stats+pm+gbc
    k_init<<<256, 1024, 0, stream>>>(x, v2, g2, ws);
    for (int l = 0; l < 8; l++) {
        int rev = (l % 2 == 0) ? 1 : 0;
        int last = (l == 7) ? 1 : 0;
        k_bin<<<256, 1024, 0, stream>>>(x, v1, g1, bn1g, bn1b, b2, ws, l, rev);
        k_step<<<1024, 256, 0, stream>>>(x, bn2g, bn2b, wf, bf, ws, out,
                                         l, rev, last);
    }
}